// Round 8
// baseline (320.857 us; speedup 1.0000x reference)
//
#include <hip/hip_runtime.h>

#define HH 16
#define SS 4096
#define DHD 128
#define BC 64         // k rows per tile; q-tile = 64 rows (16 per wave)
#define LDK 144       // bf16/row k_s: 288B (R4-measured conflict profile)
#define LDV 68        // bf16/row vt_s: 136B -> 2-way-free commit writes
#define LDPT 72       // bf16/row pT_s
#define DM (HH * DHD)

// LDS byte offsets (no LDS pointer arrays)
#define OFF_K   0
#define OFF_VT  18432
#define OFF_PT  35840
#define SMEM_SZ 45056   // 3 blocks/CU: 3*45056 = 135168 <= 163840

typedef __bf16 bf16x8_t __attribute__((ext_vector_type(8)));
typedef __bf16 bf16x4_t __attribute__((ext_vector_type(4)));
typedef float  f32x4_t  __attribute__((ext_vector_type(4)));

// LDS-only barrier: register-prefetch global loads stay in flight.
#define BAR() asm volatile("s_waitcnt lgkmcnt(0)\n\ts_barrier" ::: "memory")

__device__ __forceinline__ f32x4_t vmax4(f32x4_t a, f32x4_t b) {
    f32x4_t r;
    r[0] = fmaxf(a[0], b[0]); r[1] = fmaxf(a[1], b[1]);
    r[2] = fmaxf(a[2], b[2]); r[3] = fmaxf(a[3], b[3]);
    return r;
}

__global__ __launch_bounds__(256, 3)
void fa_fwd(const float* __restrict__ q, const float* __restrict__ k,
            const float* __restrict__ v, float* __restrict__ out)
{
    // 1024 blocks, one 64-row q-tile each, qt DESCENDING with blockIdx (LPT):
    // the per-CU work queue self-balances at ~3 resident blocks/CU.
    const int b  = blockIdx.x;
    const int qt = 63 - (b >> 4);
    const int h  = b & 15;
    const int J  = qt + 1;

    const int tid  = threadIdx.x;
    const int wave = tid >> 6;
    const int lane = tid & 63;
    const int l16  = lane & 15;
    const int quad = lane >> 4;
    const int rK   = tid >> 5;               // staging row base (0..7)
    const int c4   = tid & 31;               // staging float4 col
    const int dbase = (wave & 1) * 64;       // V-transpose staging split
    const int rbase = (wave >> 1) * 32;

    __shared__ __align__(16) char smem[SMEM_SZ];
    unsigned short* k_s  = (unsigned short*)(smem + OFF_K);
    unsigned short* vt_s = (unsigned short*)(smem + OFF_VT);
    unsigned short* pT_s = (unsigned short*)(smem + OFF_PT);

    const size_t hoff = (size_t)h * SS * DHD;
    const float* qh = q + hoff;
    const float* kh = k + hoff;
    const float* vh = v + hoff;

    // 1/sqrt(128) * log2(e): softmax in exp2 domain.
    const float scale = 0.088388347648318447f * 1.4426950408889634f;

    // ---- K/V register prefetch (R4 pattern) ----
    float4 kreg[8];
    float  vreg[8][4];
    auto issue = [&](int j) {
        const float* kb = kh + (size_t)j * BC * DHD;
        #pragma unroll
        for (int i = 0; i < 8; ++i)
            kreg[i] = ((const float4*)(kb + (size_t)(rK + i * 8) * DHD))[c4];
        const float* vb = vh + (size_t)j * BC * DHD + dbase + lane;
        #pragma unroll
        for (int p = 0; p < 8; ++p) {
            const float* vp = vb + (size_t)(rbase + p * 4) * DHD;
            vreg[p][0] = vp[0];
            vreg[p][1] = vp[DHD];
            vreg[p][2] = vp[2 * DHD];
            vreg[p][3] = vp[3 * DHD];
        }
    };

    issue(0);

    // ---- Q fragments: direct global -> registers (no LDS staging) ----
    bf16x8_t qf[4];
    {
        const float* qb = qh + (size_t)(qt * 64 + wave * 16 + l16) * DHD;
        #pragma unroll
        for (int kc = 0; kc < 4; ++kc) {
            const float* row = qb + kc * 32 + quad * 8;
            float4 a0 = *(const float4*)row;
            float4 a1 = *(const float4*)(row + 4);
            bf16x8_t f;
            f[0] = (__bf16)(a0.x * scale); f[1] = (__bf16)(a0.y * scale);
            f[2] = (__bf16)(a0.z * scale); f[3] = (__bf16)(a0.w * scale);
            f[4] = (__bf16)(a1.x * scale); f[5] = (__bf16)(a1.y * scale);
            f[6] = (__bf16)(a1.z * scale); f[7] = (__bf16)(a1.w * scale);
            qf[kc] = f;
        }
    }

    f32x4_t oacc[8];
    #pragma unroll
    for (int mt = 0; mt < 8; ++mt) oacc[mt] = (f32x4_t)(0.0f);
    float mi = -INFINITY, li = 0.0f;
    const int q_local = wave * 16 + l16;

    for (int j = 0; j < J; ++j) {
        BAR();                         // prev-iter LDS reads drained; vm in flight
        // ---- commit prefetched K ----
        #pragma unroll
        for (int i = 0; i < 8; ++i) {
            bf16x4_t bb;
            bb[0] = (__bf16)kreg[i].x; bb[1] = (__bf16)kreg[i].y;
            bb[2] = (__bf16)kreg[i].z; bb[3] = (__bf16)kreg[i].w;
            *(bf16x4_t*)&k_s[(rK + i * 8) * LDK + c4 * 4] = bb;
        }
        // ---- commit prefetched V transposed ----
        #pragma unroll
        for (int p = 0; p < 8; ++p) {
            bf16x4_t bb;
            bb[0] = (__bf16)vreg[p][0]; bb[1] = (__bf16)vreg[p][1];
            bb[2] = (__bf16)vreg[p][2]; bb[3] = (__bf16)vreg[p][3];
            *(bf16x4_t*)&vt_s[(dbase + lane) * LDV + rbase + p * 4] = bb;
        }
        if (j + 1 < J) issue(j + 1);
        BAR();

        // ---- S^T = K Q^T : 4 m-tiles (k) x 1 n-tile (q) ----
        f32x4_t sa[4];
        #pragma unroll
        for (int mt = 0; mt < 4; ++mt) sa[mt] = (f32x4_t)(0.0f);
        #pragma unroll
        for (int kc = 0; kc < 4; ++kc)
            #pragma unroll
            for (int mt = 0; mt < 4; ++mt) {
                bf16x8_t kf = *(const bf16x8_t*)
                    &k_s[(mt * 16 + l16) * LDK + kc * 32 + quad * 8];
                sa[mt] = __builtin_amdgcn_mfma_f32_16x16x32_bf16(kf, qf[kc], sa[mt], 0, 0, 0);
            }

        // ---- causal mask on the diagonal k-tile ----
        if (j == qt) {
            #pragma unroll
            for (int mt = 0; mt < 4; ++mt)
                #pragma unroll
                for (int r = 0; r < 4; ++r)
                    if (mt * 16 + quad * 4 + r > q_local) sa[mt][r] = -INFINITY;
        }

        // ---- online softmax (exp2): in-lane 16 + 2 shfls ----
        f32x4_t mv = vmax4(vmax4(sa[0], sa[1]), vmax4(sa[2], sa[3]));
        float mx = fmaxf(fmaxf(mv[0], mv[1]), fmaxf(mv[2], mv[3]));
        mx = fmaxf(mx, __shfl_xor(mx, 16));
        mx = fmaxf(mx, __shfl_xor(mx, 32));
        float mnew = fmaxf(mi, mx);
        float a = exp2f(mi - mnew);
        mi = mnew;
        bf16x4_t pkv[4];
        #pragma unroll
        for (int mt = 0; mt < 4; ++mt) {
            #pragma unroll
            for (int r = 0; r < 4; ++r) sa[mt][r] = exp2f(sa[mt][r] - mnew);
            pkv[mt][0] = (__bf16)sa[mt][0]; pkv[mt][1] = (__bf16)sa[mt][1];
            pkv[mt][2] = (__bf16)sa[mt][2]; pkv[mt][3] = (__bf16)sa[mt][3];
        }
        f32x4_t sv = (sa[0] + sa[1]) + (sa[2] + sa[3]);
        float rs = (sv[0] + sv[1]) + (sv[2] + sv[3]);
        rs += __shfl_xor(rs, 16);
        rs += __shfl_xor(rs, 32);
        li = li * a + rs;

        // ---- P^T -> LDS (wave-local rows; same-wave ds ordering) ----
        #pragma unroll
        for (int mt = 0; mt < 4; ++mt)
            *(bf16x4_t*)&pT_s[(wave * 16 + l16) * LDPT + mt * 16 + quad * 4] = pkv[mt];

        // ---- rescale O^T ----
        #pragma unroll
        for (int mt = 0; mt < 8; ++mt) {
            oacc[mt][0] *= a; oacc[mt][1] *= a;
            oacc[mt][2] *= a; oacc[mt][3] *= a;
        }

        // ---- O^T += V^T P^T : 8 m-tiles (d) x 1 n-tile (q) ----
        #pragma unroll
        for (int kc = 0; kc < 2; ++kc) {
            bf16x8_t pb = *(const bf16x8_t*)
                &pT_s[(wave * 16 + l16) * LDPT + kc * 32 + quad * 8];
            #pragma unroll
            for (int mt = 0; mt < 8; ++mt) {
                bf16x4_t vlo = *(const bf16x4_t*)
                    &vt_s[(mt * 16 + l16) * LDV + kc * 32 + quad * 8];
                bf16x4_t vhi = *(const bf16x4_t*)
                    &vt_s[(mt * 16 + l16) * LDV + kc * 32 + quad * 8 + 4];
                bf16x8_t vf = __builtin_shufflevector(vlo, vhi, 0,1,2,3,4,5,6,7);
                oacc[mt] = __builtin_amdgcn_mfma_f32_16x16x32_bf16(vf, pb, oacc[mt], 0, 0, 0);
            }
        }
    }

    // ---- epilogue: normalize + direct store (O^T layout, 16B/lane) ----
    float iv = 1.0f / li;
    float* op = out + (size_t)(qt * 64 + wave * 16 + l16) * DM + h * DHD;
    #pragma unroll
    for (int mt = 0; mt < 8; ++mt) {
        f32x4_t vv = oacc[mt];
        vv[0] *= iv; vv[1] *= iv; vv[2] *= iv; vv[3] *= iv;
        *(f32x4_t*)&op[mt * 16 + quad * 4] = vv;
    }
}

extern "C" void kernel_launch(void* const* d_in, const int* in_sizes, int n_in,
                              void* d_out, int out_size, void* d_ws, size_t ws_size,
                              hipStream_t stream) {
    const float* q = (const float*)d_in[0];
    const float* k = (const float*)d_in[1];
    const float* v = (const float*)d_in[2];
    float* out = (float*)d_out;
    fa_fwd<<<dim3((SS / 64) * HH), dim3(256), 0, stream>>>(q, k, v, out);
}

// Round 9
// 307.564 us; speedup vs baseline: 1.0432x; 1.0432x over previous
//
#include <hip/hip_runtime.h>

#define HH 16
#define SS 4096
#define DHD 128
#define BC 64         // k rows per tile; q-tile = 64 rows (16 per wave)
#define LDK 144       // bf16/row k bufs: 288B (R4-measured conflict profile)
#define LDV 68        // bf16/row vt bufs: 136B -> 2-way-free commit writes
#define LDPT 72       // bf16/row pT_s
#define DM (HH * DHD)

// LDS byte offsets (no LDS pointer arrays -> no addrspacecast initializers)
#define OFF_K0  0
#define OFF_K1  18432
#define OFF_VT0 36864
#define OFF_VT1 54272
#define OFF_PT  71680
#define SMEM_SZ 80896   // 2 blocks/CU (<= 81920)

typedef __bf16 bf16x8_t __attribute__((ext_vector_type(8)));
typedef __bf16 bf16x4_t __attribute__((ext_vector_type(4)));
typedef float  f32x4_t  __attribute__((ext_vector_type(4)));

// LDS-only barrier: register-prefetch global loads stay in flight.
#define BAR() asm volatile("s_waitcnt lgkmcnt(0)\n\ts_barrier" ::: "memory")

__device__ __forceinline__ f32x4_t vmax4(f32x4_t a, f32x4_t b) {
    f32x4_t r;
    r[0] = fmaxf(a[0], b[0]); r[1] = fmaxf(a[1], b[1]);
    r[2] = fmaxf(a[2], b[2]); r[3] = fmaxf(a[3], b[3]);
    return r;
}

__global__ __launch_bounds__(256, 2)
void fa_fwd(const float* __restrict__ q, const float* __restrict__ k,
            const float* __restrict__ v, float* __restrict__ out)
{
    // 512 EQUAL blocks: q-tiles {g, 63-g} sequential inside one block
    // (65 k-iters each) -> duration-matched co-residency, 2 blocks/CU.
    const int b   = blockIdx.x;
    const int h   = b & 15;
    const int g   = b >> 4;            // 0..31
    const int qt0 = g, qt1 = 63 - g;
    const int n0  = g + 1;             // iters in tile 0
    const int J   = 65;

    const int tid  = threadIdx.x;
    const int wave = tid >> 6;
    const int lane = tid & 63;
    const int l16  = lane & 15;
    const int quad = lane >> 4;
    const int rK   = tid >> 5;               // staging row base (0..7)
    const int c4   = tid & 31;               // staging float4 col
    const int dbase = (wave & 1) * 64;       // V-transpose staging split
    const int rbase = (wave >> 1) * 32;

    __shared__ __align__(16) char smem[SMEM_SZ];
    unsigned short* pT_s = (unsigned short*)(smem + OFF_PT);

    const size_t hoff = (size_t)h * SS * DHD;
    const float* qh = q + hoff;
    const float* kh = k + hoff;
    const float* vh = v + hoff;

    // 1/sqrt(128) * log2(e): softmax in exp2 domain.
    const float scale = 0.088388347648318447f * 1.4426950408889634f;

    // ---- K/V register prefetch ----
    float4 kreg[8];
    float  vreg[8][4];
    auto issue = [&](int j) {               // j = k-tile index within the head
        const float* kb = kh + (size_t)j * BC * DHD;
        #pragma unroll
        for (int i = 0; i < 8; ++i)
            kreg[i] = ((const float4*)(kb + (size_t)(rK + i * 8) * DHD))[c4];
        const float* vb = vh + (size_t)j * BC * DHD + dbase + lane;
        #pragma unroll
        for (int p = 0; p < 8; ++p) {
            const float* vp = vb + (size_t)(rbase + p * 4) * DHD;
            vreg[p][0] = vp[0];
            vreg[p][1] = vp[DHD];
            vreg[p][2] = vp[2 * DHD];
            vreg[p][3] = vp[3 * DHD];
        }
    };
    auto commit = [&](int buf) {            // regs -> LDS buf
        unsigned short* kd = (unsigned short*)(smem + (buf ? OFF_K1 : OFF_K0));
        unsigned short* vd = (unsigned short*)(smem + (buf ? OFF_VT1 : OFF_VT0));
        #pragma unroll
        for (int i = 0; i < 8; ++i) {
            bf16x4_t bb;
            bb[0] = (__bf16)kreg[i].x; bb[1] = (__bf16)kreg[i].y;
            bb[2] = (__bf16)kreg[i].z; bb[3] = (__bf16)kreg[i].w;
            *(bf16x4_t*)&kd[(rK + i * 8) * LDK + c4 * 4] = bb;
        }
        #pragma unroll
        for (int p = 0; p < 8; ++p) {
            bf16x4_t bb;
            bb[0] = (__bf16)vreg[p][0]; bb[1] = (__bf16)vreg[p][1];
            bb[2] = (__bf16)vreg[p][2]; bb[3] = (__bf16)vreg[p][3];
            *(bf16x4_t*)&vd[(dbase + lane) * LDV + rbase + p * 4] = bb;
        }
    };
    auto jof = [&](int i) { return i < n0 ? i : i - n0; };

    // ---- Q fragments: direct global -> registers ----
    bf16x8_t qf[4];
    auto loadQ = [&](int qt) {
        const float* qb = qh + (size_t)(qt * 64 + wave * 16 + l16) * DHD;
        #pragma unroll
        for (int kc = 0; kc < 4; ++kc) {
            const float* row = qb + kc * 32 + quad * 8;
            float4 a0 = *(const float4*)row;
            float4 a1 = *(const float4*)(row + 4);
            bf16x8_t f;
            f[0] = (__bf16)(a0.x * scale); f[1] = (__bf16)(a0.y * scale);
            f[2] = (__bf16)(a0.z * scale); f[3] = (__bf16)(a0.w * scale);
            f[4] = (__bf16)(a1.x * scale); f[5] = (__bf16)(a1.y * scale);
            f[6] = (__bf16)(a1.z * scale); f[7] = (__bf16)(a1.w * scale);
            qf[kc] = f;
        }
    };

    f32x4_t oacc[8];
    float mi, li;
    auto resetAcc = [&]() {
        #pragma unroll
        for (int mt = 0; mt < 8; ++mt) oacc[mt] = (f32x4_t)(0.0f);
        mi = -INFINITY; li = 0.0f;
    };
    auto storeTile = [&](int qt) {
        float iv = 1.0f / li;
        float* op = out + (size_t)(qt * 64 + wave * 16 + l16) * DM + h * DHD;
        #pragma unroll
        for (int mt = 0; mt < 8; ++mt) {
            f32x4_t vv = oacc[mt];
            vv[0] *= iv; vv[1] *= iv; vv[2] *= iv; vv[3] *= iv;
            *(f32x4_t*)&op[mt * 16 + quad * 4] = vv;
        }
    };

    // ---- pipeline prologue: buf0 <- tile0, regs <- tile1 ----
    issue(jof(0));
    commit(0);
    issue(jof(1));
    loadQ(qt0);
    resetAcc();
    BAR();

    for (int i = 0; i < J; ++i) {
        const int t   = (i >= n0);
        const int qtc = t ? qt1 : qt0;
        const int j   = t ? i - n0 : i;
        if (i == n0) {                 // tile switch (registers only; no sync)
            storeTile(qt0);
            resetAcc();
            loadQ(qt1);
        }

        // ---- stage NEXT tile into the other buffer (off critical path) ----
        if (i + 1 < J) commit((i + 1) & 1);
        if (i + 2 < J) issue(jof(i + 2));

        const unsigned short* k_s  =
            (const unsigned short*)(smem + ((i & 1) ? OFF_K1 : OFF_K0));
        const unsigned short* vt_s =
            (const unsigned short*)(smem + ((i & 1) ? OFF_VT1 : OFF_VT0));

        // ---- S^T = K Q^T : 4 m-tiles (k) x 1 n-tile (q) ----
        f32x4_t sa[4];
        #pragma unroll
        for (int mt = 0; mt < 4; ++mt) sa[mt] = (f32x4_t)(0.0f);
        #pragma unroll
        for (int kc = 0; kc < 4; ++kc)
            #pragma unroll
            for (int mt = 0; mt < 4; ++mt) {
                bf16x8_t kf = *(const bf16x8_t*)
                    &k_s[(mt * 16 + l16) * LDK + kc * 32 + quad * 8];
                sa[mt] = __builtin_amdgcn_mfma_f32_16x16x32_bf16(kf, qf[kc], sa[mt], 0, 0, 0);
            }

        // ---- causal mask on the diagonal k-tile ----
        if (j == qtc) {
            const int ql = wave * 16 + l16;
            #pragma unroll
            for (int mt = 0; mt < 4; ++mt)
                #pragma unroll
                for (int r = 0; r < 4; ++r)
                    if (mt * 16 + quad * 4 + r > ql) sa[mt][r] = -INFINITY;
        }

        // ---- online softmax (exp2): in-lane 16 + 2 shfls ----
        f32x4_t mv = vmax4(vmax4(sa[0], sa[1]), vmax4(sa[2], sa[3]));
        float mx = fmaxf(fmaxf(mv[0], mv[1]), fmaxf(mv[2], mv[3]));
        mx = fmaxf(mx, __shfl_xor(mx, 16));
        mx = fmaxf(mx, __shfl_xor(mx, 32));
        float mnew = fmaxf(mi, mx);
        float a = exp2f(mi - mnew);
        mi = mnew;
        bf16x4_t pkv[4];
        #pragma unroll
        for (int mt = 0; mt < 4; ++mt) {
            #pragma unroll
            for (int r = 0; r < 4; ++r) sa[mt][r] = exp2f(sa[mt][r] - mnew);
            pkv[mt][0] = (__bf16)sa[mt][0]; pkv[mt][1] = (__bf16)sa[mt][1];
            pkv[mt][2] = (__bf16)sa[mt][2]; pkv[mt][3] = (__bf16)sa[mt][3];
        }
        f32x4_t sv = (sa[0] + sa[1]) + (sa[2] + sa[3]);
        float rs = (sv[0] + sv[1]) + (sv[2] + sv[3]);
        rs += __shfl_xor(rs, 16);
        rs += __shfl_xor(rs, 32);
        li = li * a + rs;

        // ---- P^T -> LDS (wave-local rows; same-wave ds ordering) ----
        #pragma unroll
        for (int mt = 0; mt < 4; ++mt)
            *(bf16x4_t*)&pT_s[(wave * 16 + l16) * LDPT + mt * 16 + quad * 4] = pkv[mt];

        // ---- rescale O^T ----
        #pragma unroll
        for (int mt = 0; mt < 8; ++mt) {
            oacc[mt][0] *= a; oacc[mt][1] *= a;
            oacc[mt][2] *= a; oacc[mt][3] *= a;
        }

        // ---- O^T += V^T P^T : 8 m-tiles (d) x 1 n-tile (q) ----
        #pragma unroll
        for (int kc = 0; kc < 2; ++kc) {
            bf16x8_t pb = *(const bf16x8_t*)
                &pT_s[(wave * 16 + l16) * LDPT + kc * 32 + quad * 8];
            #pragma unroll
            for (int mt = 0; mt < 8; ++mt) {
                bf16x4_t vlo = *(const bf16x4_t*)
                    &vt_s[(mt * 16 + l16) * LDV + kc * 32 + quad * 8];
                bf16x4_t vhi = *(const bf16x4_t*)
                    &vt_s[(mt * 16 + l16) * LDV + kc * 32 + quad * 8 + 4];
                bf16x8_t vf = __builtin_shufflevector(vlo, vhi, 0,1,2,3,4,5,6,7);
                oacc[mt] = __builtin_amdgcn_mfma_f32_16x16x32_bf16(vf, pb, oacc[mt], 0, 0, 0);
            }
        }
        BAR();                         // single sync point per iteration
    }

    storeTile(qt1);
}

extern "C" void kernel_launch(void* const* d_in, const int* in_sizes, int n_in,
                              void* d_out, int out_size, void* d_ws, size_t ws_size,
                              hipStream_t stream) {
    const float* q = (const float*)d_in[0];
    const float* k = (const float*)d_in[1];
    const float* v = (const float*)d_in[2];
    float* out = (float*)d_out;
    fa_fwd<<<dim3((SS / 128) * HH), dim3(256), 0, stream>>>(q, k, v, out);
}